// Round 15
// baseline (113.314 us; speedup 1.0000x reference)
//
#include <hip/hip_runtime.h>
#include <hip/hip_fp16.h>

typedef __attribute__((ext_vector_type(8))) _Float16 f16x8;
typedef __attribute__((ext_vector_type(16))) float f32x16;
typedef __attribute__((ext_vector_type(4))) unsigned short u16x4;
typedef unsigned short u16;
typedef unsigned int u32;

#define MFMA32F(a,b,c) __builtin_amdgcn_mfma_f32_32x32x16_f16(a,b,c,0,0,0)

// f32 -> f16 (round-to-nearest), bit pattern as u16
__device__ __forceinline__ u16 f16rn(float x){
  return (u16)__half_as_ushort(__float2half(x));
}

__device__ __forceinline__ void gload_lds16(const void* g, void* l){
  __builtin_amdgcn_global_load_lds((const __attribute__((address_space(1))) u32*)g,
                                   (__attribute__((address_space(3))) u32*)l, 16, 0, 0);
}

// ---------- prep: c vectors, folded Wc = hw@wv, bc = hw@bv+hb, W2 -> f16 row-major ----------
__global__ __launch_bounds__(128) void prep_kernel(
    const float* __restrict__ v1, const float* __restrict__ v2,
    const float* __restrict__ mt_w1, const float* __restrict__ mt_b1,
    const float* __restrict__ mt_w2, const float* __restrict__ mt_b2,
    const float* __restrict__ mt_wv, const float* __restrict__ mt_bv,
    const float* __restrict__ mts_w1, const float* __restrict__ mts_b1,
    const float* __restrict__ mts_w2, const float* __restrict__ mts_b2,
    const float* __restrict__ mts_wv, const float* __restrict__ mts_bv,
    const float* __restrict__ ht_w, const float* __restrict__ ht_b,
    const float* __restrict__ hts_w, const float* __restrict__ hts_b,
    u16* __restrict__ w2a, u16* __restrict__ w2b,
    u16* __restrict__ wc1, u16* __restrict__ wc2,
    float* __restrict__ c1, float* __restrict__ c2,
    float* __restrict__ bc1, float* __restrict__ bc2)
{
  const int blk = blockIdx.x;
  const int t = threadIdx.x;   // 128 threads
  if (blk < 128) {
    const bool second = blk >= 64;
    const int b = blk & 63;
    const float* x  = second ? v1 : v2;
    const float* w1 = second ? mts_w1 : mt_w1;
    const float* b1 = second ? mts_b1 : mt_b1;
    const float* b2 = second ? mts_b2 : mt_b2;
    float* c = second ? c2 : c1;
    __shared__ float xr[128];
    xr[t] = x[b*128 + t];
    __syncthreads();
    float s = 0.f;
    #pragma unroll 8
    for (int k=0;k<128;k++) s += w1[t*128 + k] * xr[k];
    c[b*128 + t] = s + b1[t] - b2[t];
  } else if (blk < 384) {
    const bool second = blk >= 256;
    const int e = blk - (second ? 256 : 128);
    const float* hw = second ? hts_w : ht_w;
    const float* wv = second ? mts_wv : mt_wv;
    const float* bv = second ? mts_bv : mt_bv;
    const float* hb = second ? hts_b : ht_b;
    u16* wc = second ? wc2 : wc1;
    float* bcp = second ? bc2 : bc1;
    float s = 0.f;
    #pragma unroll 8
    for (int k=0;k<128;k++) s += hw[e*128 + k] * wv[k*128 + t];
    wc[e*128 + t] = f16rn(s);
    __shared__ float red[128];
    red[t] = hw[e*128 + t] * bv[t];
    __syncthreads();
    for (int off=64; off>0; off>>=1){ if (t<off) red[t] += red[t+off]; __syncthreads(); }
    if (t==0) bcp[e] = red[0] + hb[e];
  } else {
    const int i = (blk-384)*128 + t;
    w2a[i] = f16rn(mt_w2[i]);
    w2b[i] = f16rn(mts_w2[i]);
  }
}

// ---------- main: 1024 blocks x 512 thr, 4 tiles each ----------
// 32x32x16 f16 MFMA: each LDS b128 B-fragment feeds 2 MFMA of 32K FLOP
// (4x FLOP/LDS-byte vs 16x16 path -> LDS reads halved: 24 b128/lane/tile).
// 8 waves = 4 d'-groups x 2 s-groups; weights reg-resident (128 VGPR);
// cv/bb via laundered per-tile loads (no reg hoist). R12 barrier scheme.
// A/B frag: row/col = lane&31, k = (lane>>5)*8+e. C/D: col=lane&31,
// row = (reg&3)+8*(reg>>2)+4*(lane>>5).
__global__ __launch_bounds__(512, 2) void main_kernel(
    const u16* __restrict__ mp,
    const int* __restrict__ idx,
    const u16* __restrict__ w2a, const u16* __restrict__ w2b,
    const u16* __restrict__ wc1, const u16* __restrict__ wc2,
    const float* __restrict__ c1, const float* __restrict__ c2,
    const float* __restrict__ bc1, const float* __restrict__ bc2,
    float* __restrict__ wss)
{
  __shared__ u16 Mbuf[2][64*128];   // M double buffer (16KB each)
  __shared__ u16 P1[64*128], P2[64*128];   // pre planes (16KB each)
  __shared__ float part[4][64][3];  // 3KB

  const int tid  = threadIdx.x;
  const int wid  = tid >> 6;
  const int lane = tid & 63;
  const int l31 = lane & 31;
  const int l15 = lane & 15;
  const int h   = lane >> 5;        // 0/1: k-half
  const int dg  = wid >> 1;         // d' group: rows dg*32..+32
  const int sg  = wid & 1;          // s group: cols sg*32..+32

  // ---- prologue: f16 weights -> registers (rows dg*32+l31, k = kk*16 + h*8) ----
  f16x8 W2a[8], W2b[8], Vca[8], Vcb[8];
  {
    const int wb = (dg*32 + l31)*128 + h*8;
    #pragma unroll
    for (int kk=0;kk<8;kk++){
      W2a[kk] = *(const f16x8*)(w2a + wb + kk*16);
      W2b[kk] = *(const f16x8*)(w2b + wb + kk*16);
      Vca[kk] = *(const f16x8*)(wc1 + wb + kk*16);
      Vcb[kk] = *(const f16x8*)(wc2 + wb + kk*16);
    }
  }

  const int bid = blockIdx.x;      // 1024 blocks; b constant per block
  const int b = bid >> 4;          // 0..63
  const int sbase = (bid & 15) * 256;   // 4 tiles of 64 s each

  // ---- idx prefetch for ALL 4 tiles -> register offsets ----
  const int q = lane >> 4, sl = lane & 15;
  u32 goff[4][2];
  #pragma unroll
  for (int I=0;I<4;I++){
    #pragma unroll
    for (int j=0;j<2;j++){
      const int grow = wid*8 + j*4 + q;
      const int ridx = idx[b*4096 + sbase + I*64 + grow];
      goff[I][j] = (u32)ridx*128 + (u32)((sl ^ (grow&15))*8);
    }
  }

  #define DO_GATHER(I, BUF) {                                        \
    _Pragma("unroll")                                                \
    for (int j=0;j<2;j++)                                            \
      gload_lds16(mp + goff[I][j], &Mbuf[BUF][(wid*8 + j*4)*128]);   \
  }

  #define SCORE_OUT(I) {                                             \
    if (tid < 64){                                                   \
      float S11=0.f, S22=0.f, S12=0.f;                               \
      _Pragma("unroll")                                              \
      for (int g_=0; g_<4; g_++){                                    \
        S11 += part[g_][tid][0]; S22 += part[g_][tid][1]; S12 += part[g_][tid][2]; \
      }                                                              \
      float dot = S12 / sqrtf(S11 * S22);                            \
      wss[(size_t)b*4096 + sbase + (I)*64 + tid] = expf((dot - 1.0f) * (1.0f/0.07f)); \
    }                                                                \
  }

  DO_GATHER(0, 0);
  DO_GATHER(1, 1);

  const int rbase = (sg*32 + l31)*128;   // LDS row base for B-frags / pre-writes

  #pragma unroll
  for (int i=0; i<4; ++i){
    // B1: gather(i) landed (leave gather(i+1)'s 2 reqs in flight);
    // lgkm drain makes tile i-1's partials visible for the deferred score.
    if (i < 3) asm volatile("s_waitcnt vmcnt(2) lgkmcnt(0)" ::: "memory");
    else       asm volatile("s_waitcnt vmcnt(0) lgkmcnt(0)" ::: "memory");
    __builtin_amdgcn_s_barrier();
    __builtin_amdgcn_sched_barrier(0);

    if (i >= 1) SCORE_OUT(i-1);

    const u16* mc = &Mbuf[i&1][0];

    // ---- GEMM1 dual: T1,T2 [32d' x 32s] = reg weights x LDS M ----
    f32x16 A1 = (f32x16)(0.f), A2 = (f32x16)(0.f);
    __builtin_amdgcn_s_setprio(1);
    #pragma unroll
    for (int kk=0;kk<8;kk++){
      const int a = rbase + (((kk*2 + h) ^ l15)<<3);
      f16x8 bh = *(const f16x8*)(mc + a);
      A1 = MFMA32F(W2a[kk], bh, A1);
      A2 = MFMA32F(W2b[kk], bh, A2);
    }
    __builtin_amdgcn_s_setprio(0);

    // ---- pre1/pre2 = relu(c - T) -> P planes (laundered cv loads, no hoist) ----
    {
      const float* c1L = c1 + (size_t)b*128;
      const float* c2L = c2 + (size_t)b*128;
      asm volatile("" : "+v"(c1L), "+v"(c2L));
      #pragma unroll
      for (int g=0; g<4; g++){
        const float4 cv1 = *(const float4*)(c1L + dg*32 + 8*g + 4*h);
        const float4 cv2 = *(const float4*)(c2L + dg*32 + 8*g + 4*h);
        u16x4 h4, g4;
        #pragma unroll
        for (int r=0;r<4;r++){
          float c1r = (r==0)?cv1.x:(r==1)?cv1.y:(r==2)?cv1.z:cv1.w;
          float c2r = (r==0)?cv2.x:(r==1)?cv2.y:(r==2)?cv2.z:cv2.w;
          h4[r] = f16rn(fmaxf(c1r - A1[g*4+r], 0.f));
          g4[r] = f16rn(fmaxf(c2r - A2[g*4+r], 0.f));
        }
        const int aw = rbase + (((dg*4+g) ^ l15)<<3) + h*4;
        *(u16x4*)&P1[aw] = h4;
        *(u16x4*)&P2[aw] = g4;
      }
    }
    // B2: pre planes visible; M buf[i&1] reads drained -> free for gather(i+2)
    asm volatile("s_waitcnt lgkmcnt(0)" ::: "memory");
    __builtin_amdgcn_s_barrier();
    __builtin_amdgcn_sched_barrier(0);

    if (i < 2) DO_GATHER(i+2, i&1);   // stays in flight across next B1 (counted vmcnt)

    // ---- fused GEMM2+GEMM3 into the SAME A1/A2 ----
    A1 = (f32x16)(0.f); A2 = (f32x16)(0.f);
    __builtin_amdgcn_s_setprio(1);
    #pragma unroll
    for (int kk=0;kk<8;kk++){
      const int a = rbase + (((kk*2 + h) ^ l15)<<3);
      f16x8 p1 = *(const f16x8*)(P1 + a);
      f16x8 p2 = *(const f16x8*)(P2 + a);
      A1 = MFMA32F(Vca[kk], p1, A1);
      A2 = MFMA32F(Vcb[kk], p2, A2);
    }
    __builtin_amdgcn_s_setprio(0);

    // ---- score partials: lane holds h[d'][s], d' = dg*32+(reg&3)+8*(reg>>2)+4h, s = sg*32+l31
    {
      const float* b1L = bc1;
      const float* b2L = bc2;
      asm volatile("" : "+v"(b1L), "+v"(b2L));
      float p11=0.f, p22=0.f, p12=0.f;
      #pragma unroll
      for (int g=0; g<4; g++){
        const float4 e1 = *(const float4*)(b1L + dg*32 + 8*g + 4*h);
        const float4 e2 = *(const float4*)(b2L + dg*32 + 8*g + 4*h);
        #pragma unroll
        for (int r=0;r<4;r++){
          float ee1 = (r==0)?e1.x:(r==1)?e1.y:(r==2)?e1.z:e1.w;
          float ee2 = (r==0)?e2.x:(r==1)?e2.y:(r==2)?e2.z:e2.w;
          float v1h = A1[g*4+r] + ee1;
          float v2h = A2[g*4+r] + ee2;
          p11 += v1h*v1h; p22 += v2h*v2h; p12 += v1h*v2h;
        }
      }
      p11 += __shfl_xor(p11, 32, 64);
      p22 += __shfl_xor(p22, 32, 64);
      p12 += __shfl_xor(p12, 32, 64);
      if (lane < 32){
        part[dg][sg*32+lane][0] = p11;
        part[dg][sg*32+lane][1] = p22;
        part[dg][sg*32+lane][2] = p12;
      }
    }
    // (no B3 — partials drained+barriered at next tile's B1, or epilogue below)
  }

  // epilogue: flush last tile's score
  asm volatile("s_waitcnt lgkmcnt(0)" ::: "memory");
  __builtin_amdgcn_s_barrier();
  __builtin_amdgcn_sched_barrier(0);
  SCORE_OUT(3);

  #undef DO_GATHER
  #undef SCORE_OUT
}

// ---------- split (+ optional copy): bank -> f16 plane ----------
__global__ __launch_bounds__(256) void split_copy_kernel(const float4* __restrict__ src,
    float4* __restrict__ dst, u16x4* __restrict__ mp4, int n4, int docopy)
{
  int i = blockIdx.x*256 + threadIdx.x;
  const int stride = gridDim.x*256;
  for (; i < n4; i += stride){
    float4 f = src[i];
    if (docopy) dst[i] = f;
    u16x4 h;
    h[0] = f16rn(f.x); h[1] = f16rn(f.y); h[2] = f16rn(f.z); h[3] = f16rn(f.w);
    mp4[i] = h;
  }
}

__global__ __launch_bounds__(256) void copy_kernel(const float4* __restrict__ src,
                                                   float4* __restrict__ dst, int n4)
{
  int i = blockIdx.x*256 + threadIdx.x;
  const int stride = gridDim.x*256;
  for (; i < n4; i += stride) dst[i] = src[i];
}

__global__ __launch_bounds__(128) void update_kernel(const float* __restrict__ mem,
    const float* __restrict__ v2, const int* __restrict__ y, float* __restrict__ outmem)
{
  const int b = blockIdx.x;
  const int t = threadIdx.x;
  const int row = y[b];
  for (int b2=b+1; b2<64; ++b2) if (y[b2] == row) return;   // later duplicate wins
  float ab = 0.5f*mem[(size_t)row*128 + t] + 0.5f*v2[b*128 + t];
  __shared__ float red[2];
  float s = ab*ab;
  #pragma unroll
  for (int off=1; off<64; off<<=1) s += __shfl_xor(s, off, 64);
  if ((t & 63) == 0) red[t>>6] = s;
  __syncthreads();
  float tot = red[0] + red[1];
  outmem[(size_t)row*128 + t] = ab / sqrtf(tot);
}

// scores wss[b][s] -> out[s][b]
__global__ __launch_bounds__(256) void transpose_kernel(const float* __restrict__ wss,
                                                        float* __restrict__ out)
{
  __shared__ float tile[64][65];
  const int t = blockIdx.x;
  const int c = threadIdx.x & 63;
  const int r4 = threadIdx.x >> 6;
  #pragma unroll
  for (int i=0;i<16;i++){
    int bb = i*4 + r4;
    tile[bb][c] = wss[(size_t)bb*4096 + t*64 + c];
  }
  __syncthreads();
  #pragma unroll
  for (int i=0;i<16;i++){
    int s = i*4 + r4;
    out[(size_t)(t*64+s)*64 + c] = tile[c][s];
  }
}

extern "C" void kernel_launch(void* const* d_in, const int* in_sizes, int n_in,
                              void* d_out, int out_size, void* d_ws, size_t ws_size,
                              hipStream_t stream) {
  (void)in_sizes; (void)n_in; (void)out_size;
  const float* v1      = (const float*)d_in[0];
  const float* v2      = (const float*)d_in[1];
  const float* mem     = (const float*)d_in[2];
  const float* mt_w1   = (const float*)d_in[3];
  const float* mt_b1   = (const float*)d_in[4];
  const float* mt_w2   = (const float*)d_in[5];
  const float* mt_b2   = (const float*)d_in[6];
  const float* mt_wv   = (const float*)d_in[7];
  const float* mt_bv   = (const float*)d_in[8];
  const float* mts_w1  = (const float*)d_in[9];
  const float* mts_b1  = (const float*)d_in[10];
  const float* mts_w2  = (const float*)d_in[11];
  const float* mts_b2  = (const float*)d_in[12];
  const float* mts_wv  = (const float*)d_in[13];
  const float* mts_bv  = (const float*)d_in[14];
  const float* ht_w    = (const float*)d_in[15];
  const float* ht_b    = (const float*)d_in[16];
  const float* hts_w   = (const float*)d_in[17];
  const float* hts_b   = (const float*)d_in[18];
  const int*   y       = (const int*)d_in[19];
  const int*   idx     = (const int*)d_in[20];
  float* out = (float*)d_out;
  float* outmem = out + 262144;
  char* ws = (char*)d_ws;

  u16* w2a = (u16*)(ws + 0);        // 128*128*2 = 32KB each
  u16* w2b = (u16*)(ws + 32768);
  u16* wc1 = (u16*)(ws + 65536);
  u16* wc2 = (u16*)(ws + 98304);
  float* c1   = (float*)(ws + 131072);
  float* c2   = (float*)(ws + 163840);
  float* bc1  = (float*)(ws + 196608);
  float* bc2  = (float*)(ws + 197120);
  float* wss  = (float*)(ws + 262144);   // 64*4096 f32 = 1MB

  const size_t PLANES_OFF = 2097152;
  const size_t PLANES_BYTES = (size_t)100000 * 128 * 2;   // 25.6MB f16 plane
  const bool bigws = ws_size >= PLANES_OFF + PLANES_BYTES;
  u16* mp = bigws ? (u16*)(ws + PLANES_OFF) : (u16*)outmem;  // fallback parks plane in outmem

  // 1. bank -> f16 plane (+ fused f32 copy when plane doesn't alias outmem)
  split_copy_kernel<<<2048, 256, 0, stream>>>((const float4*)mem, (float4*)outmem,
                                              (u16x4*)mp, 3200000, bigws ? 1 : 0);
  // 2. weights/c/bc prep
  prep_kernel<<<512, 128, 0, stream>>>(v1, v2,
      mt_w1, mt_b1, mt_w2, mt_b2, mt_wv, mt_bv,
      mts_w1, mts_b1, mts_w2, mts_b2, mts_wv, mts_bv,
      ht_w, ht_b, hts_w, hts_b,
      w2a, w2b, wc1, wc2, c1, c2, bc1, bc2);
  // 3. main fused compute -> wss
  main_kernel<<<1024, 512, 0, stream>>>(mp, idx,
      w2a, w2b, wc1, wc2, c1, c2, bc1, bc2, wss);
  // 4. new_memory (fallback: plane lived in outmem, copy must run after main)
  if (!bigws)
    copy_kernel<<<2048, 256, 0, stream>>>((const float4*)mem, (float4*)outmem, 3200000);
  update_kernel<<<64, 128, 0, stream>>>(mem, v2, y, outmem);
  // 5. scores transpose into out
  transpose_kernel<<<64, 256, 0, stream>>>(wss, out);
}

// Round 16
// 100.175 us; speedup vs baseline: 1.1312x; 1.1312x over previous
//
#include <hip/hip_runtime.h>
#include <hip/hip_fp16.h>

typedef __attribute__((ext_vector_type(8))) _Float16 f16x8;
typedef __attribute__((ext_vector_type(4))) float f32x4;
typedef __attribute__((ext_vector_type(4))) unsigned short u16x4;
typedef unsigned short u16;
typedef unsigned int u32;

#define MFMA16F(a,b,c) __builtin_amdgcn_mfma_f32_16x16x32_f16(a,b,c,0,0,0)

// f32 -> f16 (round-to-nearest), bit pattern as u16
__device__ __forceinline__ u16 f16rn(float x){
  return (u16)__half_as_ushort(__float2half(x));
}

__device__ __forceinline__ void gload_lds16(const void* g, void* l){
  __builtin_amdgcn_global_load_lds((const __attribute__((address_space(1))) u32*)g,
                                   (__attribute__((address_space(3))) u32*)l, 16, 0, 0);
}

// ---------- prep: c vectors, folded Wc = hw@wv, bc = hw@bv+hb, W2 -> f16 row-major ----------
__global__ __launch_bounds__(128) void prep_kernel(
    const float* __restrict__ v1, const float* __restrict__ v2,
    const float* __restrict__ mt_w1, const float* __restrict__ mt_b1,
    const float* __restrict__ mt_w2, const float* __restrict__ mt_b2,
    const float* __restrict__ mt_wv, const float* __restrict__ mt_bv,
    const float* __restrict__ mts_w1, const float* __restrict__ mts_b1,
    const float* __restrict__ mts_w2, const float* __restrict__ mts_b2,
    const float* __restrict__ mts_wv, const float* __restrict__ mts_bv,
    const float* __restrict__ ht_w, const float* __restrict__ ht_b,
    const float* __restrict__ hts_w, const float* __restrict__ hts_b,
    u16* __restrict__ w2a, u16* __restrict__ w2b,
    u16* __restrict__ wc1, u16* __restrict__ wc2,
    float* __restrict__ c1, float* __restrict__ c2,
    float* __restrict__ bc1, float* __restrict__ bc2)
{
  const int blk = blockIdx.x;
  const int t = threadIdx.x;   // 128 threads
  if (blk < 128) {
    const bool second = blk >= 64;
    const int b = blk & 63;
    const float* x  = second ? v1 : v2;
    const float* w1 = second ? mts_w1 : mt_w1;
    const float* b1 = second ? mts_b1 : mt_b1;
    const float* b2 = second ? mts_b2 : mt_b2;
    float* c = second ? c2 : c1;
    __shared__ float xr[128];
    xr[t] = x[b*128 + t];
    __syncthreads();
    float s = 0.f;
    #pragma unroll 8
    for (int k=0;k<128;k++) s += w1[t*128 + k] * xr[k];
    c[b*128 + t] = s + b1[t] - b2[t];
  } else if (blk < 384) {
    const bool second = blk >= 256;
    const int e = blk - (second ? 256 : 128);
    const float* hw = second ? hts_w : ht_w;
    const float* wv = second ? mts_wv : mt_wv;
    const float* bv = second ? mts_bv : mt_bv;
    const float* hb = second ? hts_b : ht_b;
    u16* wc = second ? wc2 : wc1;
    float* bcp = second ? bc2 : bc1;
    float s = 0.f;
    #pragma unroll 8
    for (int k=0;k<128;k++) s += hw[e*128 + k] * wv[k*128 + t];
    wc[e*128 + t] = f16rn(s);
    __shared__ float red[128];
    red[t] = hw[e*128 + t] * bv[t];
    __syncthreads();
    for (int off=64; off>0; off>>=1){ if (t<off) red[t] += red[t+off]; __syncthreads(); }
    if (t==0) bcp[e] = red[0] + hb[e];
  } else {
    const int i = (blk-384)*128 + t;
    w2a[i] = f16rn(mt_w2[i]);
    w2b[i] = f16rn(mts_w2[i]);
  }
}

// ---------- main: 1024 blocks x 512 thr, 4 tiles each (R12 configuration) ----------
// f16 MFMA path. Reg-resident f16 weights; acc pair reused across GEMM1/GEMM23;
// idx pre-fetched; counted vmcnt keeps next gather in flight across barriers;
// deferred score (2 barriers/tile). Verified best: main ~69us.
__global__ __launch_bounds__(512, 2) void main_kernel(
    const u16* __restrict__ mp,
    const int* __restrict__ idx,
    const u16* __restrict__ w2a, const u16* __restrict__ w2b,
    const u16* __restrict__ wc1, const u16* __restrict__ wc2,
    const float* __restrict__ c1, const float* __restrict__ c2,
    const float* __restrict__ bc1, const float* __restrict__ bc2,
    float* __restrict__ wss)
{
  __shared__ u16 Mbuf[2][64*128];   // M double buffer (16KB each)
  __shared__ u16 P1[64*128], P2[64*128];   // pre planes (16KB each)
  __shared__ float part[8][64][3];  // 6KB

  const int tid  = threadIdx.x;
  const int wid  = tid >> 6;        // 0..7 -> d' slice [wid*16, wid*16+16)
  const int lane = tid & 63;
  const int lg = lane >> 4, li = lane & 15;

  // ---- prologue: f16 weights -> registers (row d'=wid*16+li, chunk k*4+lg) ----
  const int wbase = (wid*16 + li)*128 + lg*8;
  f16x8 W2a[4], W2b[4], Vca[4], Vcb[4];
  #pragma unroll
  for (int k=0;k<4;k++){
    W2a[k] = *(const f16x8*)(w2a + wbase + k*32);
    W2b[k] = *(const f16x8*)(w2b + wbase + k*32);
    Vca[k] = *(const f16x8*)(wc1 + wbase + k*32);
    Vcb[k] = *(const f16x8*)(wc2 + wbase + k*32);
  }

  const int bid = blockIdx.x;      // 1024 blocks; b constant per block
  const int b = bid >> 4;          // 0..63
  const int sbase = (bid & 15) * 256;   // 4 tiles of 64 s each

  // ---- idx prefetch for ALL 4 tiles -> register offsets ----
  const int q = lane >> 4, sl = lane & 15;
  u32 goff[4][2];
  #pragma unroll
  for (int I=0;I<4;I++){
    #pragma unroll
    for (int j=0;j<2;j++){
      const int grow = wid*8 + j*4 + q;
      const int ridx = idx[b*4096 + sbase + I*64 + grow];
      goff[I][j] = (u32)ridx*128 + (u32)((sl ^ (grow&15))*8);
    }
  }

  #define DO_GATHER(I, BUF) {                                        \
    _Pragma("unroll")                                                \
    for (int j=0;j<2;j++)                                            \
      gload_lds16(mp + goff[I][j], &Mbuf[BUF][(wid*8 + j*4)*128]);   \
  }

  #define SCORE_OUT(I) {                                             \
    if (tid < 64){                                                   \
      float S11=0.f, S22=0.f, S12=0.f;                               \
      _Pragma("unroll")                                              \
      for (int w=0; w<8; w++){                                       \
        S11 += part[w][tid][0]; S22 += part[w][tid][1]; S12 += part[w][tid][2]; \
      }                                                              \
      float dot = S12 / sqrtf(S11 * S22);                            \
      wss[(size_t)b*4096 + sbase + (I)*64 + tid] = expf((dot - 1.0f) * (1.0f/0.07f)); \
    }                                                                \
  }

  DO_GATHER(0, 0);
  DO_GATHER(1, 1);

  #pragma unroll
  for (int i=0; i<4; ++i){
    // B1: gather(i) landed (leave gather(i+1)'s 2 reqs in flight);
    // lgkm drain makes tile i-1's partials visible for the deferred score.
    if (i < 3) asm volatile("s_waitcnt vmcnt(2) lgkmcnt(0)" ::: "memory");
    else       asm volatile("s_waitcnt vmcnt(0) lgkmcnt(0)" ::: "memory");
    __builtin_amdgcn_s_barrier();
    __builtin_amdgcn_sched_barrier(0);

    // ---- deferred score for tile i-1 (part protected until after B2) ----
    if (i >= 1) SCORE_OUT(i-1);

    const u16* mc = &Mbuf[i&1][0];

    // ---- GEMM1 dual into A1/A2: T1,T2 [d' x s] = reg weights x LDS M ----
    f32x4 A1[4], A2[4];
    #pragma unroll
    for (int n=0;n<4;n++){ A1[n]=(f32x4)(0.f); A2[n]=(f32x4)(0.f); }
    #pragma unroll
    for (int k=0;k<4;k++){
      __builtin_amdgcn_s_setprio(1);
      #pragma unroll
      for (int n=0;n<4;n++){
        const int a = (n*16+li)*128 + (((k*4+lg) ^ li)<<3);
        f16x8 bh = *(const f16x8*)(mc + a);
        A1[n] = MFMA16F(W2a[k], bh, A1[n]);
        A2[n] = MFMA16F(W2b[k], bh, A2[n]);
      }
      __builtin_amdgcn_s_setprio(0);
    }

    // ---- pre1/pre2 = relu(c - T) -> P planes (b64 along d', slot-XOR swizzle) ----
    {
      const float4 cv1 = *(const float4*)(c1 + b*128 + wid*16 + lg*4);
      const float4 cv2 = *(const float4*)(c2 + b*128 + wid*16 + lg*4);
      const int c = wid*2 + (lg>>1);
      const int sub = (lg&1)*4;
      #pragma unroll
      for (int n=0;n<4;n++){
        const int row = n*16 + li;
        const int a2 = row*128 + ((c ^ li)<<3) + sub;
        u16x4 h4, g4;
        #pragma unroll
        for (int r=0;r<4;r++){
          float c1r = (r==0)?cv1.x:(r==1)?cv1.y:(r==2)?cv1.z:cv1.w;
          float c2r = (r==0)?cv2.x:(r==1)?cv2.y:(r==2)?cv2.z:cv2.w;
          h4[r] = f16rn(fmaxf(c1r - A1[n][r], 0.f));
          g4[r] = f16rn(fmaxf(c2r - A2[n][r], 0.f));
        }
        *(u16x4*)&P1[a2] = h4;
        *(u16x4*)&P2[a2] = g4;
      }
    }
    // B2: pre planes visible; M buf[i&1] reads drained -> free for gather(i+2)
    asm volatile("s_waitcnt lgkmcnt(0)" ::: "memory");
    __builtin_amdgcn_s_barrier();
    __builtin_amdgcn_sched_barrier(0);

    if (i < 2) DO_GATHER(i+2, i&1);   // stays in flight across next B1 (counted vmcnt)

    // ---- fused GEMM2+GEMM3 into the SAME A1/A2 (AGPR reuse) ----
    #pragma unroll
    for (int n=0;n<4;n++){ A1[n]=(f32x4)(0.f); A2[n]=(f32x4)(0.f); }
    #pragma unroll
    for (int k=0;k<4;k++){
      __builtin_amdgcn_s_setprio(1);
      #pragma unroll
      for (int n=0;n<4;n++){
        const int a = (n*16+li)*128 + (((k*4+lg) ^ li)<<3);
        f16x8 p1h = *(const f16x8*)(P1 + a);
        f16x8 p2h = *(const f16x8*)(P2 + a);
        A1[n] = MFMA16F(Vca[k], p1h, A1[n]);
        A2[n] = MFMA16F(Vcb[k], p2h, A2[n]);
      }
      __builtin_amdgcn_s_setprio(0);
    }

    // ---- score partials: lane holds h[d'][s], d' = wid*16+lg*4+r, s = n*16+li ----
    {
      const float4 bb1 = *(const float4*)(bc1 + wid*16 + lg*4);
      const float4 bb2 = *(const float4*)(bc2 + wid*16 + lg*4);
      #pragma unroll
      for (int n=0;n<4;n++){
        float p11=0.f, p22=0.f, p12=0.f;
        #pragma unroll
        for (int r=0;r<4;r++){
          float e1 = (r==0)?bb1.x:(r==1)?bb1.y:(r==2)?bb1.z:bb1.w;
          float e2 = (r==0)?bb2.x:(r==1)?bb2.y:(r==2)?bb2.z:bb2.w;
          float v1h = A1[n][r] + e1;
          float v2h = A2[n][r] + e2;
          p11 += v1h*v1h; p22 += v2h*v2h; p12 += v1h*v2h;
        }
        p11 += __shfl_xor(p11, 16, 64); p11 += __shfl_xor(p11, 32, 64);
        p22 += __shfl_xor(p22, 16, 64); p22 += __shfl_xor(p22, 32, 64);
        p12 += __shfl_xor(p12, 16, 64); p12 += __shfl_xor(p12, 32, 64);
        if (lane < 16){
          part[wid][n*16+li][0] = p11;
          part[wid][n*16+li][1] = p22;
          part[wid][n*16+li][2] = p12;
        }
      }
    }
    // (no B3 — partials drained+barriered at next tile's B1, or epilogue below)
  }

  // epilogue: flush last tile's score
  asm volatile("s_waitcnt lgkmcnt(0)" ::: "memory");
  __builtin_amdgcn_s_barrier();
  __builtin_amdgcn_sched_barrier(0);
  SCORE_OUT(3);

  #undef DO_GATHER
  #undef SCORE_OUT
}

// ---------- split (+ optional copy): bank -> f16 plane ----------
__global__ __launch_bounds__(256) void split_copy_kernel(const float4* __restrict__ src,
    float4* __restrict__ dst, u16x4* __restrict__ mp4, int n4, int docopy)
{
  int i = blockIdx.x*256 + threadIdx.x;
  const int stride = gridDim.x*256;
  for (; i < n4; i += stride){
    float4 f = src[i];
    if (docopy) dst[i] = f;
    u16x4 h;
    h[0] = f16rn(f.x); h[1] = f16rn(f.y); h[2] = f16rn(f.z); h[3] = f16rn(f.w);
    mp4[i] = h;
  }
}

__global__ __launch_bounds__(256) void copy_kernel(const float4* __restrict__ src,
                                                   float4* __restrict__ dst, int n4)
{
  int i = blockIdx.x*256 + threadIdx.x;
  const int stride = gridDim.x*256;
  for (; i < n4; i += stride) dst[i] = src[i];
}

__global__ __launch_bounds__(128) void update_kernel(const float* __restrict__ mem,
    const float* __restrict__ v2, const int* __restrict__ y, float* __restrict__ outmem)
{
  const int b = blockIdx.x;
  const int t = threadIdx.x;
  const int row = y[b];
  for (int b2=b+1; b2<64; ++b2) if (y[b2] == row) return;   // later duplicate wins
  float ab = 0.5f*mem[(size_t)row*128 + t] + 0.5f*v2[b*128 + t];
  __shared__ float red[2];
  float s = ab*ab;
  #pragma unroll
  for (int off=1; off<64; off<<=1) s += __shfl_xor(s, off, 64);
  if ((t & 63) == 0) red[t>>6] = s;
  __syncthreads();
  float tot = red[0] + red[1];
  outmem[(size_t)row*128 + t] = ab / sqrtf(tot);
}

// scores wss[b][s] -> out[s][b]
__global__ __launch_bounds__(256) void transpose_kernel(const float* __restrict__ wss,
                                                        float* __restrict__ out)
{
  __shared__ float tile[64][65];
  const int t = blockIdx.x;
  const int c = threadIdx.x & 63;
  const int r4 = threadIdx.x >> 6;
  #pragma unroll
  for (int i=0;i<16;i++){
    int bb = i*4 + r4;
    tile[bb][c] = wss[(size_t)bb*4096 + t*64 + c];
  }
  __syncthreads();
  #pragma unroll
  for (int i=0;i<16;i++){
    int s = i*4 + r4;
    out[(size_t)(t*64+s)*64 + c] = tile[c][s];
  }
}

extern "C" void kernel_launch(void* const* d_in, const int* in_sizes, int n_in,
                              void* d_out, int out_size, void* d_ws, size_t ws_size,
                              hipStream_t stream) {
  (void)in_sizes; (void)n_in; (void)out_size;
  const float* v1      = (const float*)d_in[0];
  const float* v2      = (const float*)d_in[1];
  const float* mem     = (const float*)d_in[2];
  const float* mt_w1   = (const float*)d_in[3];
  const float* mt_b1   = (const float*)d_in[4];
  const float* mt_w2   = (const float*)d_in[5];
  const float* mt_b2   = (const float*)d_in[6];
  const float* mt_wv   = (const float*)d_in[7];
  const float* mt_bv   = (const float*)d_in[8];
  const float* mts_w1  = (const float*)d_in[9];
  const float* mts_b1  = (const float*)d_in[10];
  const float* mts_w2  = (const float*)d_in[11];
  const float* mts_b2  = (const float*)d_in[12];
  const float* mts_wv  = (const float*)d_in[13];
  const float* mts_bv  = (const float*)d_in[14];
  const float* ht_w    = (const float*)d_in[15];
  const float* ht_b    = (const float*)d_in[16];
  const float* hts_w   = (const float*)d_in[17];
  const float* hts_b   = (const float*)d_in[18];
  const int*   y       = (const int*)d_in[19];
  const int*   idx     = (const int*)d_in[20];
  float* out = (float*)d_out;
  float* outmem = out + 262144;
  char* ws = (char*)d_ws;

  u16* w2a = (u16*)(ws + 0);        // 128*128*2 = 32KB each
  u16* w2b = (u16*)(ws + 32768);
  u16* wc1 = (u16*)(ws + 65536);
  u16* wc2 = (u16*)(ws + 98304);
  float* c1   = (float*)(ws + 131072);
  float* c2   = (float*)(ws + 163840);
  float* bc1  = (float*)(ws + 196608);
  float* bc2  = (float*)(ws + 197120);
  float* wss  = (float*)(ws + 262144);   // 64*4096 f32 = 1MB

  const size_t PLANES_OFF = 2097152;
  const size_t PLANES_BYTES = (size_t)100000 * 128 * 2;   // 25.6MB f16 plane
  const bool bigws = ws_size >= PLANES_OFF + PLANES_BYTES;
  u16* mp = bigws ? (u16*)(ws + PLANES_OFF) : (u16*)outmem;  // fallback parks plane in outmem

  // 1. convert bank to f16 plane (+ fused copy when plane doesn't alias outmem)
  split_copy_kernel<<<2048, 256, 0, stream>>>((const float4*)mem, (float4*)outmem,
                                              (u16x4*)mp, 3200000, bigws ? 1 : 0);
  // 2. weights/c/bc prep
  prep_kernel<<<512, 128, 0, stream>>>(v1, v2,
      mt_w1, mt_b1, mt_w2, mt_b2, mt_wv, mt_bv,
      mts_w1, mts_b1, mts_w2, mts_b2, mts_wv, mts_bv,
      ht_w, ht_b, hts_w, hts_b,
      w2a, w2b, wc1, wc2, c1, c2, bc1, bc2);
  // 3. main fused compute -> wss
  main_kernel<<<1024, 512, 0, stream>>>(mp, idx,
      w2a, w2b, wc1, wc2, c1, c2, bc1, bc2, wss);
  // 4. new_memory
  if (!bigws)
    copy_kernel<<<2048, 256, 0, stream>>>((const float4*)mem, (float4*)outmem, 3200000);
  update_kernel<<<64, 128, 0, stream>>>(mem, v2, y, outmem);
  // 5. scores transpose into out
  transpose_kernel<<<64, 256, 0, stream>>>(wss, out);
}

// Round 17
// 94.916 us; speedup vs baseline: 1.1938x; 1.0554x over previous
//
#include <hip/hip_runtime.h>
#include <hip/hip_fp16.h>

typedef __attribute__((ext_vector_type(8))) _Float16 f16x8;
typedef __attribute__((ext_vector_type(4))) float f32x4;
typedef __attribute__((ext_vector_type(4))) unsigned short u16x4;
typedef unsigned short u16;
typedef unsigned int u32;

#define MFMA16F(a,b,c) __builtin_amdgcn_mfma_f32_16x16x32_f16(a,b,c,0,0,0)

// f32 -> f16 (round-to-nearest), bit pattern as u16
__device__ __forceinline__ u16 f16rn(float x){
  return (u16)__half_as_ushort(__float2half(x));
}

__device__ __forceinline__ void gload_lds16(const void* g, void* l){
  __builtin_amdgcn_global_load_lds((const __attribute__((address_space(1))) u32*)g,
                                   (__attribute__((address_space(3))) u32*)l, 16, 0, 0);
}

// ---------- fused aux: prep (blocks 0..511) ∥ bank->f16 plane + f32 copy (512..2559) ----------
// prep and split_copy are independent; fusing them into one grid overlaps prep's
// ~5us under the copy's ~18us of HBM time (stream would otherwise serialize them).
// prep roles use 128 active lanes; barriers are executed by ALL 256 threads and
// branches are block-uniform (no divergence hazards).
__global__ __launch_bounds__(256) void fused_aux_kernel(
    const float4* __restrict__ src, float4* __restrict__ dst,
    u16x4* __restrict__ mp4, int n4, int docopy,
    const float* __restrict__ v1, const float* __restrict__ v2,
    const float* __restrict__ mt_w1, const float* __restrict__ mt_b1,
    const float* __restrict__ mt_w2, const float* __restrict__ mt_b2,
    const float* __restrict__ mt_wv, const float* __restrict__ mt_bv,
    const float* __restrict__ mts_w1, const float* __restrict__ mts_b1,
    const float* __restrict__ mts_w2, const float* __restrict__ mts_b2,
    const float* __restrict__ mts_wv, const float* __restrict__ mts_bv,
    const float* __restrict__ ht_w, const float* __restrict__ ht_b,
    const float* __restrict__ hts_w, const float* __restrict__ hts_b,
    u16* __restrict__ w2a, u16* __restrict__ w2b,
    u16* __restrict__ wc1, u16* __restrict__ wc2,
    float* __restrict__ c1, float* __restrict__ c2,
    float* __restrict__ bc1, float* __restrict__ bc2)
{
  __shared__ float xr[128];
  __shared__ float red[128];
  const int blk = blockIdx.x;
  const int tid = threadIdx.x;

  if (blk >= 512){
    // ---- split/copy role: grid-stride over the f32 bank ----
    int i = (blk - 512)*256 + tid;
    const int stride = 2048*256;
    for (; i < n4; i += stride){
      float4 f = src[i];
      if (docopy) dst[i] = f;
      u16x4 h;
      h[0] = f16rn(f.x); h[1] = f16rn(f.y); h[2] = f16rn(f.z); h[3] = f16rn(f.w);
      mp4[i] = h;
    }
    return;
  }

  // ---- prep roles (virtual 128-thread blocks; t<128 active) ----
  const int pb = blk;
  const bool act = tid < 128;
  const int t = tid & 127;
  if (pb < 128) {
    // c[b][d] = sum_k w1[d][k]*x[b][k] + b1[d] - b2[d]
    const bool second = pb >= 64;
    const int b = pb & 63;
    const float* x  = second ? v1 : v2;
    const float* w1 = second ? mts_w1 : mt_w1;
    const float* b1 = second ? mts_b1 : mt_b1;
    const float* b2 = second ? mts_b2 : mt_b2;
    float* c = second ? c2 : c1;
    if (act) xr[t] = x[b*128 + t];
    __syncthreads();
    if (act){
      float s = 0.f;
      #pragma unroll 8
      for (int k=0;k<128;k++) s += w1[t*128 + k] * xr[k];
      c[b*128 + t] = s + b1[t] - b2[t];
    }
  } else if (pb < 384) {
    // Wc row e: Wc[e][d] = sum_k hw[e][k]*wv[k][d];  bc[e] = hw[e]·bv + hb[e]
    const bool second = pb >= 256;
    const int e = pb - (second ? 256 : 128);
    const float* hw = second ? hts_w : ht_w;
    const float* wv = second ? mts_wv : mt_wv;
    const float* bv = second ? mts_bv : mt_bv;
    const float* hb = second ? hts_b : ht_b;
    u16* wc = second ? wc2 : wc1;
    float* bcp = second ? bc2 : bc1;
    if (act){
      float s = 0.f;
      #pragma unroll 8
      for (int k=0;k<128;k++) s += hw[e*128 + k] * wv[k*128 + t];
      wc[e*128 + t] = f16rn(s);
      red[t] = hw[e*128 + t] * bv[t];
    }
    __syncthreads();
    for (int off=64; off>0; off>>=1){
      if (act && t < off) red[t] += red[t+off];
      __syncthreads();
    }
    if (act && t == 0) bcp[e] = red[0] + hb[e];
  } else {
    // W2 -> f16: 128 virtual blocks x 128 lanes = 16384 elems, both matrices
    if (act){
      const int i = (pb-384)*128 + t;
      w2a[i] = f16rn(mt_w2[i]);
      w2b[i] = f16rn(mts_w2[i]);
    }
  }
}

// ---------- main: 1024 blocks x 512 thr, 4 tiles each (R12 configuration, verified) ----------
// f16 MFMA path. Reg-resident f16 weights; acc pair reused across GEMM1/GEMM23;
// idx pre-fetched; counted vmcnt keeps next gather in flight across barriers;
// deferred score (2 barriers/tile). Verified best: main ~69us.
__global__ __launch_bounds__(512, 2) void main_kernel(
    const u16* __restrict__ mp,
    const int* __restrict__ idx,
    const u16* __restrict__ w2a, const u16* __restrict__ w2b,
    const u16* __restrict__ wc1, const u16* __restrict__ wc2,
    const float* __restrict__ c1, const float* __restrict__ c2,
    const float* __restrict__ bc1, const float* __restrict__ bc2,
    float* __restrict__ wss)
{
  __shared__ u16 Mbuf[2][64*128];   // M double buffer (16KB each)
  __shared__ u16 P1[64*128], P2[64*128];   // pre planes (16KB each)
  __shared__ float part[8][64][3];  // 6KB

  const int tid  = threadIdx.x;
  const int wid  = tid >> 6;        // 0..7 -> d' slice [wid*16, wid*16+16)
  const int lane = tid & 63;
  const int lg = lane >> 4, li = lane & 15;

  // ---- prologue: f16 weights -> registers (row d'=wid*16+li, chunk k*4+lg) ----
  const int wbase = (wid*16 + li)*128 + lg*8;
  f16x8 W2a[4], W2b[4], Vca[4], Vcb[4];
  #pragma unroll
  for (int k=0;k<4;k++){
    W2a[k] = *(const f16x8*)(w2a + wbase + k*32);
    W2b[k] = *(const f16x8*)(w2b + wbase + k*32);
    Vca[k] = *(const f16x8*)(wc1 + wbase + k*32);
    Vcb[k] = *(const f16x8*)(wc2 + wbase + k*32);
  }

  const int bid = blockIdx.x;      // 1024 blocks; b constant per block
  const int b = bid >> 4;          // 0..63
  const int sbase = (bid & 15) * 256;   // 4 tiles of 64 s each

  // ---- idx prefetch for ALL 4 tiles -> register offsets ----
  const int q = lane >> 4, sl = lane & 15;
  u32 goff[4][2];
  #pragma unroll
  for (int I=0;I<4;I++){
    #pragma unroll
    for (int j=0;j<2;j++){
      const int grow = wid*8 + j*4 + q;
      const int ridx = idx[b*4096 + sbase + I*64 + grow];
      goff[I][j] = (u32)ridx*128 + (u32)((sl ^ (grow&15))*8);
    }
  }

  #define DO_GATHER(I, BUF) {                                        \
    _Pragma("unroll")                                                \
    for (int j=0;j<2;j++)                                            \
      gload_lds16(mp + goff[I][j], &Mbuf[BUF][(wid*8 + j*4)*128]);   \
  }

  #define SCORE_OUT(I) {                                             \
    if (tid < 64){                                                   \
      float S11=0.f, S22=0.f, S12=0.f;                               \
      _Pragma("unroll")                                              \
      for (int w=0; w<8; w++){                                       \
        S11 += part[w][tid][0]; S22 += part[w][tid][1]; S12 += part[w][tid][2]; \
      }                                                              \
      float dot = S12 / sqrtf(S11 * S22);                            \
      wss[(size_t)b*4096 + sbase + (I)*64 + tid] = expf((dot - 1.0f) * (1.0f/0.07f)); \
    }                                                                \
  }

  DO_GATHER(0, 0);
  DO_GATHER(1, 1);

  #pragma unroll
  for (int i=0; i<4; ++i){
    // B1: gather(i) landed (leave gather(i+1)'s 2 reqs in flight);
    // lgkm drain makes tile i-1's partials visible for the deferred score.
    if (i < 3) asm volatile("s_waitcnt vmcnt(2) lgkmcnt(0)" ::: "memory");
    else       asm volatile("s_waitcnt vmcnt(0) lgkmcnt(0)" ::: "memory");
    __builtin_amdgcn_s_barrier();
    __builtin_amdgcn_sched_barrier(0);

    // ---- deferred score for tile i-1 (part protected until after B2) ----
    if (i >= 1) SCORE_OUT(i-1);

    const u16* mc = &Mbuf[i&1][0];

    // ---- GEMM1 dual into A1/A2: T1,T2 [d' x s] = reg weights x LDS M ----
    f32x4 A1[4], A2[4];
    #pragma unroll
    for (int n=0;n<4;n++){ A1[n]=(f32x4)(0.f); A2[n]=(f32x4)(0.f); }
    #pragma unroll
    for (int k=0;k<4;k++){
      __builtin_amdgcn_s_setprio(1);
      #pragma unroll
      for (int n=0;n<4;n++){
        const int a = (n*16+li)*128 + (((k*4+lg) ^ li)<<3);
        f16x8 bh = *(const f16x8*)(mc + a);
        A1[n] = MFMA16F(W2a[k], bh, A1[n]);
        A2[n] = MFMA16F(W2b[k], bh, A2[n]);
      }
      __builtin_amdgcn_s_setprio(0);
    }

    // ---- pre1/pre2 = relu(c - T) -> P planes (b64 along d', slot-XOR swizzle) ----
    {
      const float4 cv1 = *(const float4*)(c1 + b*128 + wid*16 + lg*4);
      const float4 cv2 = *(const float4*)(c2 + b*128 + wid*16 + lg*4);
      const int c = wid*2 + (lg>>1);
      const int sub = (lg&1)*4;
      #pragma unroll
      for (int n=0;n<4;n++){
        const int row = n*16 + li;
        const int a2 = row*128 + ((c ^ li)<<3) + sub;
        u16x4 h4, g4;
        #pragma unroll
        for (int r=0;r<4;r++){
          float c1r = (r==0)?cv1.x:(r==1)?cv1.y:(r==2)?cv1.z:cv1.w;
          float c2r = (r==0)?cv2.x:(r==1)?cv2.y:(r==2)?cv2.z:cv2.w;
          h4[r] = f16rn(fmaxf(c1r - A1[n][r], 0.f));
          g4[r] = f16rn(fmaxf(c2r - A2[n][r], 0.f));
        }
        *(u16x4*)&P1[a2] = h4;
        *(u16x4*)&P2[a2] = g4;
      }
    }
    // B2: pre planes visible; M buf[i&1] reads drained -> free for gather(i+2)
    asm volatile("s_waitcnt lgkmcnt(0)" ::: "memory");
    __builtin_amdgcn_s_barrier();
    __builtin_amdgcn_sched_barrier(0);

    if (i < 2) DO_GATHER(i+2, i&1);   // stays in flight across next B1 (counted vmcnt)

    // ---- fused GEMM2+GEMM3 into the SAME A1/A2 (AGPR reuse) ----
    #pragma unroll
    for (int n=0;n<4;n++){ A1[n]=(f32x4)(0.f); A2[n]=(f32x4)(0.f); }
    #pragma unroll
    for (int k=0;k<4;k++){
      __builtin_amdgcn_s_setprio(1);
      #pragma unroll
      for (int n=0;n<4;n++){
        const int a = (n*16+li)*128 + (((k*4+lg) ^ li)<<3);
        f16x8 p1h = *(const f16x8*)(P1 + a);
        f16x8 p2h = *(const f16x8*)(P2 + a);
        A1[n] = MFMA16F(Vca[k], p1h, A1[n]);
        A2[n] = MFMA16F(Vcb[k], p2h, A2[n]);
      }
      __builtin_amdgcn_s_setprio(0);
    }

    // ---- score partials: lane holds h[d'][s], d' = wid*16+lg*4+r, s = n*16+li ----
    {
      const float4 bb1 = *(const float4*)(bc1 + wid*16 + lg*4);
      const float4 bb2 = *(const float4*)(bc2 + wid*16 + lg*4);
      #pragma unroll
      for (int n=0;n<4;n++){
        float p11=0.f, p22=0.f, p12=0.f;
        #pragma unroll
        for (int r=0;r<4;r++){
          float e1 = (r==0)?bb1.x:(r==1)?bb1.y:(r==2)?bb1.z:bb1.w;
          float e2 = (r==0)?bb2.x:(r==1)?bb2.y:(r==2)?bb2.z:bb2.w;
          float v1h = A1[n][r] + e1;
          float v2h = A2[n][r] + e2;
          p11 += v1h*v1h; p22 += v2h*v2h; p12 += v1h*v2h;
        }
        p11 += __shfl_xor(p11, 16, 64); p11 += __shfl_xor(p11, 32, 64);
        p22 += __shfl_xor(p22, 16, 64); p22 += __shfl_xor(p22, 32, 64);
        p12 += __shfl_xor(p12, 16, 64); p12 += __shfl_xor(p12, 32, 64);
        if (lane < 16){
          part[wid][n*16+li][0] = p11;
          part[wid][n*16+li][1] = p22;
          part[wid][n*16+li][2] = p12;
        }
      }
    }
    // (no B3 — partials drained+barriered at next tile's B1, or epilogue below)
  }

  // epilogue: flush last tile's score
  asm volatile("s_waitcnt lgkmcnt(0)" ::: "memory");
  __builtin_amdgcn_s_barrier();
  __builtin_amdgcn_sched_barrier(0);
  SCORE_OUT(3);

  #undef DO_GATHER
  #undef SCORE_OUT
}

__global__ __launch_bounds__(256) void copy_kernel(const float4* __restrict__ src,
                                                   float4* __restrict__ dst, int n4)
{
  int i = blockIdx.x*256 + threadIdx.x;
  const int stride = gridDim.x*256;
  for (; i < n4; i += stride) dst[i] = src[i];
}

__global__ __launch_bounds__(128) void update_kernel(const float* __restrict__ mem,
    const float* __restrict__ v2, const int* __restrict__ y, float* __restrict__ outmem)
{
  const int b = blockIdx.x;
  const int t = threadIdx.x;
  const int row = y[b];
  for (int b2=b+1; b2<64; ++b2) if (y[b2] == row) return;   // later duplicate wins
  float ab = 0.5f*mem[(size_t)row*128 + t] + 0.5f*v2[b*128 + t];
  __shared__ float red[2];
  float s = ab*ab;
  #pragma unroll
  for (int off=1; off<64; off<<=1) s += __shfl_xor(s, off, 64);
  if ((t & 63) == 0) red[t>>6] = s;
  __syncthreads();
  float tot = red[0] + red[1];
  outmem[(size_t)row*128 + t] = ab / sqrtf(tot);
}

// scores wss[b][s] -> out[s][b]
__global__ __launch_bounds__(256) void transpose_kernel(const float* __restrict__ wss,
                                                        float* __restrict__ out)
{
  __shared__ float tile[64][65];
  const int t = blockIdx.x;
  const int c = threadIdx.x & 63;
  const int r4 = threadIdx.x >> 6;
  #pragma unroll
  for (int i=0;i<16;i++){
    int bb = i*4 + r4;
    tile[bb][c] = wss[(size_t)bb*4096 + t*64 + c];
  }
  __syncthreads();
  #pragma unroll
  for (int i=0;i<16;i++){
    int s = i*4 + r4;
    out[(size_t)(t*64+s)*64 + c] = tile[c][s];
  }
}

extern "C" void kernel_launch(void* const* d_in, const int* in_sizes, int n_in,
                              void* d_out, int out_size, void* d_ws, size_t ws_size,
                              hipStream_t stream) {
  (void)in_sizes; (void)n_in; (void)out_size;
  const float* v1      = (const float*)d_in[0];
  const float* v2      = (const float*)d_in[1];
  const float* mem     = (const float*)d_in[2];
  const float* mt_w1   = (const float*)d_in[3];
  const float* mt_b1   = (const float*)d_in[4];
  const float* mt_w2   = (const float*)d_in[5];
  const float* mt_b2   = (const float*)d_in[6];
  const float* mt_wv   = (const float*)d_in[7];
  const float* mt_bv   = (const float*)d_in[8];
  const float* mts_w1  = (const float*)d_in[9];
  const float* mts_b1  = (const float*)d_in[10];
  const float* mts_w2  = (const float*)d_in[11];
  const float* mts_b2  = (const float*)d_in[12];
  const float* mts_wv  = (const float*)d_in[13];
  const float* mts_bv  = (const float*)d_in[14];
  const float* ht_w    = (const float*)d_in[15];
  const float* ht_b    = (const float*)d_in[16];
  const float* hts_w   = (const float*)d_in[17];
  const float* hts_b   = (const float*)d_in[18];
  const int*   y       = (const int*)d_in[19];
  const int*   idx     = (const int*)d_in[20];
  float* out = (float*)d_out;
  float* outmem = out + 262144;
  char* ws = (char*)d_ws;

  u16* w2a = (u16*)(ws + 0);        // 128*128*2 = 32KB each
  u16* w2b = (u16*)(ws + 32768);
  u16* wc1 = (u16*)(ws + 65536);
  u16* wc2 = (u16*)(ws + 98304);
  float* c1   = (float*)(ws + 131072);
  float* c2   = (float*)(ws + 163840);
  float* bc1  = (float*)(ws + 196608);
  float* bc2  = (float*)(ws + 197120);
  float* wss  = (float*)(ws + 262144);   // 64*4096 f32 = 1MB

  const size_t PLANES_OFF = 2097152;
  const size_t PLANES_BYTES = (size_t)100000 * 128 * 2;   // 25.6MB f16 plane
  const bool bigws = ws_size >= PLANES_OFF + PLANES_BYTES;
  u16* mp = bigws ? (u16*)(ws + PLANES_OFF) : (u16*)outmem;  // fallback parks plane in outmem

  // 1. fused: prep (512 blocks) ∥ bank -> f16 plane + f32 copy (2048 blocks)
  fused_aux_kernel<<<2560, 256, 0, stream>>>((const float4*)mem, (float4*)outmem,
      (u16x4*)mp, 3200000, bigws ? 1 : 0,
      v1, v2, mt_w1, mt_b1, mt_w2, mt_b2, mt_wv, mt_bv,
      mts_w1, mts_b1, mts_w2, mts_b2, mts_wv, mts_bv,
      ht_w, ht_b, hts_w, hts_b,
      w2a, w2b, wc1, wc2, c1, c2, bc1, bc2);
  // 2. main fused compute -> wss
  main_kernel<<<1024, 512, 0, stream>>>(mp, idx,
      w2a, w2b, wc1, wc2, c1, c2, bc1, bc2, wss);
  // 3. new_memory (fallback: plane lived in outmem, copy must run after main)
  if (!bigws)
    copy_kernel<<<2048, 256, 0, stream>>>((const float4*)mem, (float4*)outmem, 3200000);
  update_kernel<<<64, 128, 0, stream>>>(mem, v2, y, outmem);
  // 4. scores transpose into out
  transpose_kernel<<<64, 256, 0, stream>>>(wss, out);
}

// Round 18
// 91.938 us; speedup vs baseline: 1.2325x; 1.0324x over previous
//
#include <hip/hip_runtime.h>
#include <hip/hip_fp16.h>

typedef __attribute__((ext_vector_type(8))) _Float16 f16x8;
typedef __attribute__((ext_vector_type(4))) float f32x4;
typedef __attribute__((ext_vector_type(4))) unsigned short u16x4;
typedef unsigned short u16;
typedef unsigned int u32;

#define MFMA16F(a,b,c) __builtin_amdgcn_mfma_f32_16x16x32_f16(a,b,c,0,0,0)

// f32 -> f16 (round-to-nearest), bit pattern as u16
__device__ __forceinline__ u16 f16rn(float x){
  return (u16)__half_as_ushort(__float2half(x));
}

__device__ __forceinline__ void gload_lds16(const void* g, void* l){
  __builtin_amdgcn_global_load_lds((const __attribute__((address_space(1))) u32*)g,
                                   (__attribute__((address_space(3))) u32*)l, 16, 0, 0);
}

// ---------- fused aux: prep (blocks 0..511) ∥ bank->f16 plane + f32 copy (512..2559) ----------
__global__ __launch_bounds__(256) void fused_aux_kernel(
    const float4* __restrict__ src, float4* __restrict__ dst,
    u16x4* __restrict__ mp4, int n4, int docopy,
    const float* __restrict__ v1, const float* __restrict__ v2,
    const float* __restrict__ mt_w1, const float* __restrict__ mt_b1,
    const float* __restrict__ mt_w2, const float* __restrict__ mt_b2,
    const float* __restrict__ mt_wv, const float* __restrict__ mt_bv,
    const float* __restrict__ mts_w1, const float* __restrict__ mts_b1,
    const float* __restrict__ mts_w2, const float* __restrict__ mts_b2,
    const float* __restrict__ mts_wv, const float* __restrict__ mts_bv,
    const float* __restrict__ ht_w, const float* __restrict__ ht_b,
    const float* __restrict__ hts_w, const float* __restrict__ hts_b,
    u16* __restrict__ w2a, u16* __restrict__ w2b,
    u16* __restrict__ wc1, u16* __restrict__ wc2,
    float* __restrict__ c1, float* __restrict__ c2,
    float* __restrict__ bc1, float* __restrict__ bc2)
{
  __shared__ float xr[128];
  __shared__ float red[128];
  const int blk = blockIdx.x;
  const int tid = threadIdx.x;

  if (blk >= 512){
    // ---- split/copy role: grid-stride over the f32 bank ----
    int i = (blk - 512)*256 + tid;
    const int stride = 2048*256;
    for (; i < n4; i += stride){
      float4 f = src[i];
      if (docopy) dst[i] = f;
      u16x4 h;
      h[0] = f16rn(f.x); h[1] = f16rn(f.y); h[2] = f16rn(f.z); h[3] = f16rn(f.w);
      mp4[i] = h;
    }
    return;
  }

  // ---- prep roles (virtual 128-thread blocks; t<128 active) ----
  const int pb = blk;
  const bool act = tid < 128;
  const int t = tid & 127;
  if (pb < 128) {
    const bool second = pb >= 64;
    const int b = pb & 63;
    const float* x  = second ? v1 : v2;
    const float* w1 = second ? mts_w1 : mt_w1;
    const float* b1 = second ? mts_b1 : mt_b1;
    const float* b2 = second ? mts_b2 : mt_b2;
    float* c = second ? c2 : c1;
    if (act) xr[t] = x[b*128 + t];
    __syncthreads();
    if (act){
      float s = 0.f;
      #pragma unroll 8
      for (int k=0;k<128;k++) s += w1[t*128 + k] * xr[k];
      c[b*128 + t] = s + b1[t] - b2[t];
    }
  } else if (pb < 384) {
    const bool second = pb >= 256;
    const int e = pb - (second ? 256 : 128);
    const float* hw = second ? hts_w : ht_w;
    const float* wv = second ? mts_wv : mt_wv;
    const float* bv = second ? mts_bv : mt_bv;
    const float* hb = second ? hts_b : ht_b;
    u16* wc = second ? wc2 : wc1;
    float* bcp = second ? bc2 : bc1;
    if (act){
      float s = 0.f;
      #pragma unroll 8
      for (int k=0;k<128;k++) s += hw[e*128 + k] * wv[k*128 + t];
      wc[e*128 + t] = f16rn(s);
      red[t] = hw[e*128 + t] * bv[t];
    }
    __syncthreads();
    for (int off=64; off>0; off>>=1){
      if (act && t < off) red[t] += red[t+off];
      __syncthreads();
    }
    if (act && t == 0) bcp[e] = red[0] + hb[e];
  } else {
    if (act){
      const int i = (pb-384)*128 + t;
      w2a[i] = f16rn(mt_w2[i]);
      w2b[i] = f16rn(mts_w2[i]);
    }
  }
}

// ---------- main: 1024 blocks x 512 thr, 4 tiles each (R12 configuration, verified) ----------
// f16 MFMA path. Reg-resident f16 weights; acc pair reused across GEMM1/GEMM23;
// idx pre-fetched; counted vmcnt keeps next gather in flight across barriers;
// deferred score (2 barriers/tile). Verified best: main ~69us.
__global__ __launch_bounds__(512, 2) void main_kernel(
    const u16* __restrict__ mp,
    const int* __restrict__ idx,
    const u16* __restrict__ w2a, const u16* __restrict__ w2b,
    const u16* __restrict__ wc1, const u16* __restrict__ wc2,
    const float* __restrict__ c1, const float* __restrict__ c2,
    const float* __restrict__ bc1, const float* __restrict__ bc2,
    float* __restrict__ wss)
{
  __shared__ u16 Mbuf[2][64*128];   // M double buffer (16KB each)
  __shared__ u16 P1[64*128], P2[64*128];   // pre planes (16KB each)
  __shared__ float part[8][64][3];  // 6KB

  const int tid  = threadIdx.x;
  const int wid  = tid >> 6;        // 0..7 -> d' slice [wid*16, wid*16+16)
  const int lane = tid & 63;
  const int lg = lane >> 4, li = lane & 15;

  // ---- prologue: f16 weights -> registers (row d'=wid*16+li, chunk k*4+lg) ----
  const int wbase = (wid*16 + li)*128 + lg*8;
  f16x8 W2a[4], W2b[4], Vca[4], Vcb[4];
  #pragma unroll
  for (int k=0;k<4;k++){
    W2a[k] = *(const f16x8*)(w2a + wbase + k*32);
    W2b[k] = *(const f16x8*)(w2b + wbase + k*32);
    Vca[k] = *(const f16x8*)(wc1 + wbase + k*32);
    Vcb[k] = *(const f16x8*)(wc2 + wbase + k*32);
  }

  const int bid = blockIdx.x;      // 1024 blocks; b constant per block
  const int b = bid >> 4;          // 0..63
  const int sbase = (bid & 15) * 256;   // 4 tiles of 64 s each

  // ---- idx prefetch for ALL 4 tiles -> register offsets ----
  const int q = lane >> 4, sl = lane & 15;
  u32 goff[4][2];
  #pragma unroll
  for (int I=0;I<4;I++){
    #pragma unroll
    for (int j=0;j<2;j++){
      const int grow = wid*8 + j*4 + q;
      const int ridx = idx[b*4096 + sbase + I*64 + grow];
      goff[I][j] = (u32)ridx*128 + (u32)((sl ^ (grow&15))*8);
    }
  }

  #define DO_GATHER(I, BUF) {                                        \
    _Pragma("unroll")                                                \
    for (int j=0;j<2;j++)                                            \
      gload_lds16(mp + goff[I][j], &Mbuf[BUF][(wid*8 + j*4)*128]);   \
  }

  #define SCORE_OUT(I) {                                             \
    if (tid < 64){                                                   \
      float S11=0.f, S22=0.f, S12=0.f;                               \
      _Pragma("unroll")                                              \
      for (int w=0; w<8; w++){                                       \
        S11 += part[w][tid][0]; S22 += part[w][tid][1]; S12 += part[w][tid][2]; \
      }                                                              \
      float dot = S12 / sqrtf(S11 * S22);                            \
      wss[(size_t)b*4096 + sbase + (I)*64 + tid] = expf((dot - 1.0f) * (1.0f/0.07f)); \
    }                                                                \
  }

  DO_GATHER(0, 0);
  DO_GATHER(1, 1);

  #pragma unroll
  for (int i=0; i<4; ++i){
    // B1: gather(i) landed (leave gather(i+1)'s 2 reqs in flight);
    // lgkm drain makes tile i-1's partials visible for the deferred score.
    if (i < 3) asm volatile("s_waitcnt vmcnt(2) lgkmcnt(0)" ::: "memory");
    else       asm volatile("s_waitcnt vmcnt(0) lgkmcnt(0)" ::: "memory");
    __builtin_amdgcn_s_barrier();
    __builtin_amdgcn_sched_barrier(0);

    // ---- deferred score for tile i-1 (part protected until after B2) ----
    if (i >= 1) SCORE_OUT(i-1);

    const u16* mc = &Mbuf[i&1][0];

    // ---- GEMM1 dual into A1/A2: T1,T2 [d' x s] = reg weights x LDS M ----
    f32x4 A1[4], A2[4];
    #pragma unroll
    for (int n=0;n<4;n++){ A1[n]=(f32x4)(0.f); A2[n]=(f32x4)(0.f); }
    #pragma unroll
    for (int k=0;k<4;k++){
      __builtin_amdgcn_s_setprio(1);
      #pragma unroll
      for (int n=0;n<4;n++){
        const int a = (n*16+li)*128 + (((k*4+lg) ^ li)<<3);
        f16x8 bh = *(const f16x8*)(mc + a);
        A1[n] = MFMA16F(W2a[k], bh, A1[n]);
        A2[n] = MFMA16F(W2b[k], bh, A2[n]);
      }
      __builtin_amdgcn_s_setprio(0);
    }

    // ---- pre1/pre2 = relu(c - T) -> P planes (b64 along d', slot-XOR swizzle) ----
    {
      const float4 cv1 = *(const float4*)(c1 + b*128 + wid*16 + lg*4);
      const float4 cv2 = *(const float4*)(c2 + b*128 + wid*16 + lg*4);
      const int c = wid*2 + (lg>>1);
      const int sub = (lg&1)*4;
      #pragma unroll
      for (int n=0;n<4;n++){
        const int row = n*16 + li;
        const int a2 = row*128 + ((c ^ li)<<3) + sub;
        u16x4 h4, g4;
        #pragma unroll
        for (int r=0;r<4;r++){
          float c1r = (r==0)?cv1.x:(r==1)?cv1.y:(r==2)?cv1.z:cv1.w;
          float c2r = (r==0)?cv2.x:(r==1)?cv2.y:(r==2)?cv2.z:cv2.w;
          h4[r] = f16rn(fmaxf(c1r - A1[n][r], 0.f));
          g4[r] = f16rn(fmaxf(c2r - A2[n][r], 0.f));
        }
        *(u16x4*)&P1[a2] = h4;
        *(u16x4*)&P2[a2] = g4;
      }
    }
    // B2: pre planes visible; M buf[i&1] reads drained -> free for gather(i+2)
    asm volatile("s_waitcnt lgkmcnt(0)" ::: "memory");
    __builtin_amdgcn_s_barrier();
    __builtin_amdgcn_sched_barrier(0);

    if (i < 2) DO_GATHER(i+2, i&1);   // stays in flight across next B1 (counted vmcnt)

    // ---- fused GEMM2+GEMM3 into the SAME A1/A2 (AGPR reuse) ----
    #pragma unroll
    for (int n=0;n<4;n++){ A1[n]=(f32x4)(0.f); A2[n]=(f32x4)(0.f); }
    #pragma unroll
    for (int k=0;k<4;k++){
      __builtin_amdgcn_s_setprio(1);
      #pragma unroll
      for (int n=0;n<4;n++){
        const int a = (n*16+li)*128 + (((k*4+lg) ^ li)<<3);
        f16x8 p1h = *(const f16x8*)(P1 + a);
        f16x8 p2h = *(const f16x8*)(P2 + a);
        A1[n] = MFMA16F(Vca[k], p1h, A1[n]);
        A2[n] = MFMA16F(Vcb[k], p2h, A2[n]);
      }
      __builtin_amdgcn_s_setprio(0);
    }

    // ---- score partials: lane holds h[d'][s], d' = wid*16+lg*4+r, s = n*16+li ----
    {
      const float4 bb1 = *(const float4*)(bc1 + wid*16 + lg*4);
      const float4 bb2 = *(const float4*)(bc2 + wid*16 + lg*4);
      #pragma unroll
      for (int n=0;n<4;n++){
        float p11=0.f, p22=0.f, p12=0.f;
        #pragma unroll
        for (int r=0;r<4;r++){
          float e1 = (r==0)?bb1.x:(r==1)?bb1.y:(r==2)?bb1.z:bb1.w;
          float e2 = (r==0)?bb2.x:(r==1)?bb2.y:(r==2)?bb2.z:bb2.w;
          float v1h = A1[n][r] + e1;
          float v2h = A2[n][r] + e2;
          p11 += v1h*v1h; p22 += v2h*v2h; p12 += v1h*v2h;
        }
        p11 += __shfl_xor(p11, 16, 64); p11 += __shfl_xor(p11, 32, 64);
        p22 += __shfl_xor(p22, 16, 64); p22 += __shfl_xor(p22, 32, 64);
        p12 += __shfl_xor(p12, 16, 64); p12 += __shfl_xor(p12, 32, 64);
        if (lane < 16){
          part[wid][n*16+li][0] = p11;
          part[wid][n*16+li][1] = p22;
          part[wid][n*16+li][2] = p12;
        }
      }
    }
    // (no B3 — partials drained+barriered at next tile's B1, or epilogue below)
  }

  // epilogue: flush last tile's score
  asm volatile("s_waitcnt lgkmcnt(0)" ::: "memory");
  __builtin_amdgcn_s_barrier();
  __builtin_amdgcn_sched_barrier(0);
  SCORE_OUT(3);

  #undef DO_GATHER
  #undef SCORE_OUT
}

__global__ __launch_bounds__(256) void copy_kernel(const float4* __restrict__ src,
                                                   float4* __restrict__ dst, int n4)
{
  int i = blockIdx.x*256 + threadIdx.x;
  const int stride = gridDim.x*256;
  for (; i < n4; i += stride) dst[i] = src[i];
}

// ---------- tail: transpose (blocks 0..63) + momentum update (blocks 64..127) ----------
__global__ __launch_bounds__(256) void tail_kernel(
    const float* __restrict__ wss, float* __restrict__ out,
    const float* __restrict__ mem, const float* __restrict__ v2,
    const int* __restrict__ y, float* __restrict__ outmem)
{
  const int blk = blockIdx.x;
  const int tid = threadIdx.x;
  if (blk < 64){
    // scores wss[b][s] -> out[s][b]
    __shared__ float tile[64][65];
    const int t = blk;
    const int c = tid & 63;
    const int r4 = tid >> 6;
    #pragma unroll
    for (int i=0;i<16;i++){
      int bb = i*4 + r4;
      tile[bb][c] = wss[(size_t)bb*4096 + t*64 + c];
    }
    __syncthreads();
    #pragma unroll
    for (int i=0;i<16;i++){
      int s = i*4 + r4;
      out[(size_t)(t*64+s)*64 + c] = tile[c][s];
    }
  } else {
    // momentum update for row y[b] (last-wins on duplicates; block-uniform branch)
    __shared__ float red[2];
    const int b = blk - 64;
    const int row = y[b];
    for (int b2=b+1; b2<64; ++b2) if (y[b2] == row) return;
    const bool act = tid < 128;
    const int t = tid & 127;
    float ab = 0.f, s = 0.f;
    if (act){
      ab = 0.5f*mem[(size_t)row*128 + t] + 0.5f*v2[b*128 + t];
      s = ab*ab;
      #pragma unroll
      for (int off=1; off<64; off<<=1) s += __shfl_xor(s, off, 64);
      if ((t & 63) == 0) red[t>>6] = s;
    }
    __syncthreads();
    if (act){
      float tot = red[0] + red[1];
      outmem[(size_t)row*128 + t] = ab / sqrtf(tot);
    }
  }
}

extern "C" void kernel_launch(void* const* d_in, const int* in_sizes, int n_in,
                              void* d_out, int out_size, void* d_ws, size_t ws_size,
                              hipStream_t stream) {
  (void)in_sizes; (void)n_in; (void)out_size;
  const float* v1      = (const float*)d_in[0];
  const float* v2      = (const float*)d_in[1];
  const float* mem     = (const float*)d_in[2];
  const float* mt_w1   = (const float*)d_in[3];
  const float* mt_b1   = (const float*)d_in[4];
  const float* mt_w2   = (const float*)d_in[5];
  const float* mt_b2   = (const float*)d_in[6];
  const float* mt_wv   = (const float*)d_in[7];
  const float* mt_bv   = (const float*)d_in[8];
  const float* mts_w1  = (const float*)d_in[9];
  const float* mts_b1  = (const float*)d_in[10];
  const float* mts_w2  = (const float*)d_in[11];
  const float* mts_b2  = (const float*)d_in[12];
  const float* mts_wv  = (const float*)d_in[13];
  const float* mts_bv  = (const float*)d_in[14];
  const float* ht_w    = (const float*)d_in[15];
  const float* ht_b    = (const float*)d_in[16];
  const float* hts_w   = (const float*)d_in[17];
  const float* hts_b   = (const float*)d_in[18];
  const int*   y       = (const int*)d_in[19];
  const int*   idx     = (const int*)d_in[20];
  float* out = (float*)d_out;
  float* outmem = out + 262144;
  char* ws = (char*)d_ws;

  u16* w2a = (u16*)(ws + 0);        // 128*128*2 = 32KB each
  u16* w2b = (u16*)(ws + 32768);
  u16* wc1 = (u16*)(ws + 65536);
  u16* wc2 = (u16*)(ws + 98304);
  float* c1   = (float*)(ws + 131072);
  float* c2   = (float*)(ws + 163840);
  float* bc1  = (float*)(ws + 196608);
  float* bc2  = (float*)(ws + 197120);
  float* wss  = (float*)(ws + 262144);   // 64*4096 f32 = 1MB

  const size_t PLANES_OFF = 2097152;
  const size_t PLANES_BYTES = (size_t)100000 * 128 * 2;   // 25.6MB f16 plane
  const bool bigws = ws_size >= PLANES_OFF + PLANES_BYTES;
  u16* mp = bigws ? (u16*)(ws + PLANES_OFF) : (u16*)outmem;  // fallback parks plane in outmem

  // 1. fused: prep (512 blocks) ∥ bank -> f16 plane + f32 copy (2048 blocks)
  fused_aux_kernel<<<2560, 256, 0, stream>>>((const float4*)mem, (float4*)outmem,
      (u16x4*)mp, 3200000, bigws ? 1 : 0,
      v1, v2, mt_w1, mt_b1, mt_w2, mt_b2, mt_wv, mt_bv,
      mts_w1, mts_b1, mts_w2, mts_b2, mts_wv, mts_bv,
      ht_w, ht_b, hts_w, hts_b,
      w2a, w2b, wc1, wc2, c1, c2, bc1, bc2);
  // 2. main fused compute -> wss
  main_kernel<<<1024, 512, 0, stream>>>(mp, idx,
      w2a, w2b, wc1, wc2, c1, c2, bc1, bc2, wss);
  // 3. fallback copy (plane lived in outmem; must run after main)
  if (!bigws)
    copy_kernel<<<2048, 256, 0, stream>>>((const float4*)mem, (float4*)outmem, 3200000);
  // 4. tail: transpose + momentum update in one launch
  tail_kernel<<<128, 256, 0, stream>>>(wss, out, mem, v2, y, outmem);
}